// Round 8
// baseline (322.474 us; speedup 1.0000x reference)
//
#include <hip/hip_runtime.h>
#include <hip/hip_bf16.h>

// SpatialBottleneck — bf16 MFMA implicit-GEMM (NHWC).
// Round 12 (= r11 with the inline-asm cvt_pk replaced by hip_bf16 header
// intrinsics; two consecutive container failures -> hedge the only exotic
// element). Per-instruction cost round: r9/r10 pipeline rewrites moved total
// by only ~6 µs -> per-step time is busy-work, not stall. conv1's step was
// dominated by software f2bf (~80 VALU/thread/step) in the fused fp32->bf16
// transpose staging. Now: __float22bfloat162_rn (compiler lowers to HW
// v_cvt_pk_bf16_f32, RNE — m240) in convW1 + bf16 epilogues; border_zero
// merged into prep_w; XCD-pairing swizzle for conv1/conv2 (co-tile pair of
// same px-tile -> same XCD -> second X pass served by L2 not L3).

#define BK 64
#define WAITVM(N) asm volatile("s_waitcnt vmcnt(" #N ")" ::: "memory")

typedef __attribute__((ext_vector_type(8))) short short8;
typedef __attribute__((ext_vector_type(4))) float f32x4;

__device__ inline unsigned short f2bf(float f) {
    unsigned int u = __float_as_uint(f);
    u += 0x7fff + ((u >> 16) & 1);            // RNE (cold paths only)
    return (unsigned short)(u >> 16);
}

// Packed fp32->bf16 (RNE) via standard header; compiler emits the HW
// packed convert on gfx950 (m240: hand-written asm is slower, not needed).
__device__ inline unsigned cvt_pk_bf16(float a, float b) {
    __hip_bfloat162 h = __float22bfloat162_rn(make_float2(a, b)); // x=lo, y=hi
    return *reinterpret_cast<unsigned*>(&h);
}

__device__ inline void gload16(const unsigned short* g, unsigned short* l) {
    __builtin_amdgcn_global_load_lds(
        (const __attribute__((address_space(1))) unsigned int*)g,
        (__attribute__((address_space(3))) unsigned int*)l, 16, 0, 0);
}

// ---------------- prep: weights -> bf16, w2 -> [tap][co][ci]; BN fold;
// + y1p border zero (merged, saves a dispatch) ----------------
__global__ __launch_bounds__(256) void prep_w(
    const float* __restrict__ w1, const float* __restrict__ w2, const float* __restrict__ w3,
    const float* g1, const float* b1, const float* m1, const float* v1,
    const float* g2, const float* b2, const float* m2, const float* v2,
    const float* g3, const float* b3, const float* m3, const float* v3,
    unsigned short* __restrict__ Wb1, unsigned short* __restrict__ Wt2,
    unsigned short* __restrict__ Wb3,
    float* __restrict__ bn1, float* __restrict__ bn2, float* __restrict__ bn3,
    uint4* __restrict__ y1p) {
    int i = blockIdx.x * 256 + threadIdx.x;
    if (i < 262144) Wb1[i] = f2bf(w1[i]);
    if (i < 589824) {
        int kw = i % 3, t1 = i / 3;
        int kh = t1 % 3, t2 = t1 / 3;
        int ci = t2 & 255, co = t2 >> 8;
        Wt2[(size_t)((kh * 3 + kw) * 256 + co) * 256 + ci] = f2bf(w2[i]);
    }
    if (i < 262144) Wb3[i] = f2bf(w3[i]);
    if (i < 256) { float s = g1[i] * rsqrtf(v1[i]); bn1[i] = s; bn1[256 + i] = b1[i] - m1[i] * s; }
    if (i < 256) { float s = g2[i] * rsqrtf(v2[i]); bn2[i] = s; bn2[256 + i] = b2[i] - m2[i] * s; }
    if (i < 1024) { float s = g3[i] * rsqrtf(v3[i]); bn3[i] = s; bn3[1024 + i] = b3[i] - m3[i] * s; }
    // y1p border zero: 118784 = 32 img * 116 border cells * 32 uint4
    if (i < 118784) {
        int ch8 = i & 31;
        int t = i >> 5;
        int cell = t % 116;
        int n = t / 116;
        int h, w;
        if (cell < 30)      { h = 0;          w = cell; }
        else if (cell < 60) { h = 29;         w = cell - 30; }
        else if (cell < 88) { h = cell - 59;  w = 0; }
        else                { h = cell - 87;  w = 29; }
        y1p[((size_t)n * 900 + h * 30 + w) * 32 + ch8] = make_uint4(0u, 0u, 0u, 0u);
    }
}

// ---------------- MFMA implicit-GEMM conv body (counted-vmcnt pipeline) ----------------
// LAYER 1: x fp32 NCHW in (fused transpose/convert), y1p padded NHWC bf16 out
// LAYER 2: y1p in (9-tap), y2 NHWC bf16 out
// LAYER 3: y2 in, fp32 NCHW out + residual
template <int CX, int NTAPS, int LAYER, int NT, int BMT>
__device__ __forceinline__ void conv_body(
    const float* __restrict__ Xf,
    const unsigned short* __restrict__ Xg, const unsigned short* __restrict__ Wg,
    const float* __restrict__ bn, int nco,
    const float* __restrict__ residual,
    unsigned short* __restrict__ obf, float* __restrict__ ofp) {
    constexpr int KSTEPS = CX / BK;               // k0 steps per tap
    constexpr int NSTEP = NTAPS * KSTEPS;         // 16 / 36 / 4
    constexpr int XB = BMT * BK * 2;              // bytes per X buffer
    constexpr int WB = NT * BK * 2;               // bytes per W buffer
    constexpr int STAGEB = 2 * (XB + WB);         // 48 KB (l1/l2), 64 KB (l3)
    constexpr int EPIB = (LAYER == 3) ? 64 * 132 * 4 : 64 * (NT + 8) * 2;
    constexpr int SMEMB = STAGEB > EPIB ? STAGEB : EPIB;
    constexpr int NWJ = BMT / 32;                 // px fragments per wave
    constexpr int WR = NT / 32;                   // W staging rounds (4)
    constexpr int XR = BMT / 32;                  // X staging rounds (l2/l3)

    __shared__ __align__(16) char smem[SMEMB];
    unsigned short* const Xs0 = (unsigned short*)smem;
    unsigned short* const Xs1 = (unsigned short*)(smem + XB);
    unsigned short* const Ws0 = (unsigned short*)(smem + 2 * XB);
    unsigned short* const Ws1 = (unsigned short*)(smem + 2 * XB + WB);

    const int tid = threadIdx.x;
    const int wave = tid >> 6, lane = tid & 63;
    const int quad = lane >> 4, l15 = lane & 15;

    // XCD-pairing swizzle (layers 1/2, grid = 784 1-D): the two co-tiles of a
    // px-tile land on the same XCD (b and b+8 -> same b%8) within 8 slots.
    int bx, by;
    if (LAYER == 3) { bx = blockIdx.x; by = blockIdx.y; }
    else            { int b = blockIdx.x; bx = (b >> 4) * 8 + (b & 7); by = (b >> 3) & 1; }
    const int Pb = bx * BMT;
    const int cb = by * NT;
    const int wco = (wave & 1) * 64;
    const int wpx = (wave >> 1) * (BMT / 2);

    // ---- staging precompute ----
    size_t wro[WR];                               // W: per-round global row offset
    #pragma unroll
    for (int t = 0; t < WR; ++t) {
        int slot = t * 256 + tid;
        int row = slot >> 3;
        int c = slot & 7;
        wro[t] = (size_t)(cb + row) * CX + ((c ^ (row & 7)) * 8);
    }

    int cso[4];
    size_t xrow[4];
    if (LAYER != 1) {
        #pragma unroll
        for (int t = 0; t < XR; ++t) {
            int slot = t * 256 + tid;
            int row = slot >> 3;
            int c = slot & 7;
            cso[t] = ((c ^ (row & 7)) * 8);
            if (LAYER == 2) {
                int P = Pb + row;
                int n = P / 784, rem = P - n * 784;
                int h = rem / 28, w = rem - h * 28;
                xrow[t] = (size_t)n * 900 + h * 30 + w;   // padded base (tap adds kh*30+kw)
            } else {
                xrow[t] = (size_t)(Pb + row);
            }
        }
    }

    // LAYER 1: coalesced transpose staging (4-lane groups read 64B contiguous)
    const int cpl = (lane >> 2) + (wave & 1) * 16;   // channel-pair 0..31
    size_t xbase[2];
    int plr[2];
    if (LAYER == 1) {
        #pragma unroll
        for (int r = 0; r < 2; ++r) {
            int quarter = (wave >> 1) + 2 * r;       // 0..3
            int pl = quarter * 16 + (lane & 3) * 4;  // 0..60
            int P = Pb + pl;
            int n = P / 784, p = P - n * 784;        // float4 never crosses n (784%4==0)
            plr[r] = pl;
            xbase[r] = ((size_t)n * 1024 + 2 * cpl) * 784 + p;
        }
    }

    // ---- stage helpers ----
    auto stageW = [&](int s, unsigned short* wsb) {
        int tap = (NTAPS == 1) ? 0 : (s / KSTEPS);
        int k0 = (s - tap * KSTEPS) * BK;
        const unsigned short* Wtap = Wg + (size_t)tap * 256 * CX;
        #pragma unroll
        for (int t = 0; t < WR; ++t)
            gload16(Wtap + wro[t] + k0, wsb + (t * 256 + wave * 64) * 8);
    };
    auto stageX = [&](int s, unsigned short* xsb) {   // layers 2/3
        int tap = (NTAPS == 1) ? 0 : (s / KSTEPS);
        int k0 = (s - tap * KSTEPS) * BK;
        int tapofs = (NTAPS == 9) ? ((tap / 3) * 30 + (tap % 3)) : 0;
        #pragma unroll
        for (int t = 0; t < XR; ++t)
            gload16(Xg + (xrow[t] + tapofs) * (size_t)CX + k0 + cso[t],
                    xsb + (t * 256 + wave * 64) * 8);
    };
    float4 xa[2], xb[2];                              // layer-1 in-flight regs
    auto loadX1 = [&](int s) {
        size_t k0 = (size_t)s * BK;
        #pragma unroll
        for (int r = 0; r < 2; ++r) {
            const float* src = Xf + xbase[r] + k0 * 784;
            xa[r] = *(const float4*)src;
            xb[r] = *(const float4*)(src + 784);
        }
    };
    auto convW1 = [&](unsigned short* xsb) {
        #pragma unroll
        for (int r = 0; r < 2; ++r) {
            float av[4] = {xa[r].x, xa[r].y, xa[r].z, xa[r].w};
            float bv[4] = {xb[r].x, xb[r].y, xb[r].z, xb[r].w};
            #pragma unroll
            for (int j = 0; j < 4; ++j) {
                unsigned u = cvt_pk_bf16(av[j], bv[j]);   // HW RNE pack
                int row = plr[r] + j;
                int dw = row * 32 + (((cpl >> 2) ^ (row & 7)) << 2) + (cpl & 3);
                ((unsigned*)xsb)[dw] = u;
            }
        }
    };

    f32x4 acc[4][NWJ];
    #pragma unroll
    for (int i = 0; i < 4; ++i)
        #pragma unroll
        for (int j = 0; j < NWJ; ++j)
            acc[i][j] = (f32x4){0.f, 0.f, 0.f, 0.f};

    auto compute = [&](const unsigned short* xsb, const unsigned short* wsb) {
        #pragma unroll
        for (int kk = 0; kk < BK; kk += 32) {
            short8 af[4], bf[NWJ];
            const int cbase = kk >> 3;            // 0 or 4
            #pragma unroll
            for (int wi = 0; wi < 4; ++wi) {
                int row = wco + wi * 16 + l15;
                int ch = (cbase + quad) ^ (row & 7);
                af[wi] = *(const short8*)(wsb + (row * 8 + ch) * 8);
            }
            #pragma unroll
            for (int wj = 0; wj < NWJ; ++wj) {
                int row = wpx + wj * 16 + l15;
                int ch = (cbase + quad) ^ (row & 7);
                bf[wj] = *(const short8*)(xsb + (row * 8 + ch) * 8);
            }
            #pragma unroll
            for (int wi = 0; wi < 4; ++wi)
                #pragma unroll
                for (int wj = 0; wj < NWJ; ++wj)
                    acc[wi][wj] = __builtin_amdgcn_mfma_f32_16x16x32_bf16(
                        af[wi], bf[wj], acc[wi][wj], 0, 0, 0);
        }
    };

    // ---- prologue: batch(0) into buffer 0 ----
    if (LAYER == 1) loadX1(0);
    stageW(0, Ws0);
    if (LAYER == 1) convW1(Xs0);                  // compiler waits on xa/xb regs
    else            stageX(0, Xs0);

    // ---- counted-vmcnt pipelined loop ----
    int cur = 0;
    #pragma unroll 1
    for (int s = 0; s < NSTEP; ++s) {
        unsigned short* xc = cur ? Xs1 : Xs0;
        unsigned short* wc = cur ? Ws1 : Ws0;
        unsigned short* xn = cur ? Xs0 : Xs1;
        unsigned short* wn = cur ? Ws0 : Ws1;
        const bool pre = (s + 1 < NSTEP);
        if (pre) {
            if (LAYER == 1) loadX1(s + 1);        // 4 float4 (oldest in batch)
            stageW(s + 1, wn);                    // 4 gload_lds
            if (LAYER != 1) stageX(s + 1, xn);    // 2 (l2) / 4 (l3) gload_lds
        }
        // Wait: batch(s) landed; batch(s+1) (B instrs) stays in flight.
        if (pre) {
            if constexpr (LAYER == 2) WAITVM(6);
            else                      WAITVM(8);
        } else {
            WAITVM(0);
        }
        __builtin_amdgcn_sched_barrier(0);
        __builtin_amdgcn_s_barrier();             // A: buffers for step s visible
        compute(xc, wc);
        if (LAYER == 1 && pre) convW1(xn);        // write-late: cvt_pk + ds_write
        if (LAYER == 1) asm volatile("s_waitcnt lgkmcnt(0)" ::: "memory");
        __builtin_amdgcn_s_barrier();             // B: compute(s) done; xn writes visible
        __builtin_amdgcn_sched_barrier(0);
        cur ^= 1;
    }

    __syncthreads();   // epilogue smem reuse

    if (LAYER == 3) {
        // fp32 NCHW + residual + ReLU, two co-half passes through LDS [64][132] f32
        float* ep = (float*)smem;
        #pragma unroll
        for (int pass = 0; pass < 2; ++pass) {
            if ((wave & 1) == pass) {
                #pragma unroll
                for (int wi = 0; wi < 4; ++wi) {
                    int co0 = cb + wco + wi * 16 + quad * 4;
                    f32x4 sc = *(const f32x4*)(bn + co0);
                    f32x4 bi = *(const f32x4*)(bn + nco + co0);
                    int cr0 = wi * 16 + quad * 4;          // 0..63 local co row
                    #pragma unroll
                    for (int wj = 0; wj < 4; ++wj) {
                        int px = wpx + wj * 16 + l15;      // 0..127
                        #pragma unroll
                        for (int r = 0; r < 4; ++r)
                            ep[(cr0 + r) * 132 + px] = fmaf(acc[wi][wj][r], sc[r], bi[r]);
                    }
                }
            }
            __syncthreads();
            {
                int cr = tid >> 2;                         // 0..63
                int cg = tid & 3;
                int co = cb + pass * 64 + cr;
                #pragma unroll
                for (int k = 0; k < 8; ++k) {
                    int px4 = (cg + 4 * k) * 4;            // 0..124
                    f32x4 v = *(const f32x4*)(ep + cr * 132 + px4);
                    int P = Pb + px4;
                    int n = P / 784, p = P - n * 784;
                    size_t off = ((size_t)n * 1024 + co) * 784 + p;
                    float4 rs = *(const float4*)(residual + off);
                    float4 o;
                    o.x = v[0] + rs.x; o.x = o.x > 0.f ? o.x : 0.f;
                    o.y = v[1] + rs.y; o.y = o.y > 0.f ? o.y : 0.f;
                    o.z = v[2] + rs.z; o.z = o.z > 0.f ? o.z : 0.f;
                    o.w = v[3] + rs.w; o.w = o.w > 0.f ? o.w : 0.f;
                    *(float4*)(ofp + off) = o;
                }
            }
            __syncthreads();
        }
    } else {
        // bf16 NHWC (+BN+ReLU), single pass (BMT=64 px) through LDS [64][NT+8] ushort
        constexpr int EPW = NT + 8;                // 136
        unsigned short* ep = (unsigned short*)smem;
        #pragma unroll
        for (int wi = 0; wi < 4; ++wi) {
            int co0 = cb + wco + wi * 16 + quad * 4;
            f32x4 sc = *(const f32x4*)(bn + co0);
            f32x4 bi = *(const f32x4*)(bn + nco + co0);
            int col = wco + wi * 16 + quad * 4;    // 0..127 local co
            #pragma unroll
            for (int wj = 0; wj < NWJ; ++wj) {
                int pxl = wpx + wj * 16 + l15;     // 0..63
                float v0 = fmaf(acc[wi][wj][0], sc[0], bi[0]); v0 = v0 > 0.f ? v0 : 0.f;
                float v1 = fmaf(acc[wi][wj][1], sc[1], bi[1]); v1 = v1 > 0.f ? v1 : 0.f;
                float v2 = fmaf(acc[wi][wj][2], sc[2], bi[2]); v2 = v2 > 0.f ? v2 : 0.f;
                float v3 = fmaf(acc[wi][wj][3], sc[3], bi[3]); v3 = v3 > 0.f ? v3 : 0.f;
                uint2 pk;
                pk.x = cvt_pk_bf16(v0, v1);
                pk.y = cvt_pk_bf16(v2, v3);
                *(uint2*)(ep + pxl * EPW + col) = pk;
            }
        }
        __syncthreads();
        {
            int pxl = tid >> 2;                    // 0..63
            int cg = tid & 3;
            int P = Pb + pxl;
            size_t orow;
            if (LAYER == 1) {
                int n = P / 784, rem = P - n * 784;
                int h = rem / 28, w = rem - h * 28;
                orow = (size_t)n * 900 + (h + 1) * 30 + (w + 1);
            } else {
                orow = (size_t)P;
            }
            #pragma unroll
            for (int k = 0; k < NT / 32; ++k) {
                int cc = (cg + 4 * k) * 8;         // ushort offset 0..120
                uint4 v = *(const uint4*)(ep + pxl * EPW + cc);
                *(uint4*)(obf + orow * 256 + cb + cc) = v;
            }
        }
    }
}

__global__ __launch_bounds__(256) void conv1_mfma(
    const float* __restrict__ Xf, const unsigned short* __restrict__ Wg,
    const float* __restrict__ bn, unsigned short* __restrict__ obf) {
    conv_body<1024, 1, 1, 128, 64>(Xf, nullptr, Wg, bn, 256, nullptr, obf, nullptr);
}
__global__ __launch_bounds__(256) void conv2_mfma(
    const unsigned short* __restrict__ Xg, const unsigned short* __restrict__ Wg,
    const float* __restrict__ bn, unsigned short* __restrict__ obf) {
    conv_body<256, 9, 2, 128, 64>(nullptr, Xg, Wg, bn, 256, nullptr, obf, nullptr);
}
__global__ __launch_bounds__(256) void conv3_mfma(
    const unsigned short* __restrict__ Xg, const unsigned short* __restrict__ Wg,
    const float* __restrict__ bn, const float* __restrict__ residual,
    float* __restrict__ ofp) {
    conv_body<256, 1, 3, 128, 128>(nullptr, Xg, Wg, bn, 1024, residual, nullptr, ofp);
}

extern "C" void kernel_launch(void* const* d_in, const int* in_sizes, int n_in,
                              void* d_out, int out_size, void* d_ws, size_t ws_size,
                              hipStream_t stream) {
    const float* x  = (const float*)d_in[0];
    const float* w1 = (const float*)d_in[1];
    const float* w2 = (const float*)d_in[2];
    const float* w3 = (const float*)d_in[3];
    const float* g1 = (const float*)d_in[4];  const float* b1 = (const float*)d_in[5];
    const float* m1 = (const float*)d_in[6];  const float* v1 = (const float*)d_in[7];
    const float* g2 = (const float*)d_in[8];  const float* b2 = (const float*)d_in[9];
    const float* m2 = (const float*)d_in[10]; const float* v2 = (const float*)d_in[11];
    const float* g3 = (const float*)d_in[12]; const float* b3 = (const float*)d_in[13];
    const float* m3 = (const float*)d_in[14]; const float* v3 = (const float*)d_in[15];
    float* out = (float*)d_out;

    char* ws = (char*)d_ws;
    unsigned short* y1p = (unsigned short*)(ws);                    // 32*900*256*2 = 14,745,600
    unsigned short* y2  = (unsigned short*)(ws + 14745600);         // 25088*256*2  = 12,845,056
    unsigned short* Wb1 = (unsigned short*)(ws + 27590656);         // 524,288
    unsigned short* Wt2 = (unsigned short*)(ws + 28114944);         // 1,179,648
    unsigned short* Wb3 = (unsigned short*)(ws + 29294592);         // 524,288
    float* bn1 = (float*)(ws + 29818880);                           // 2 KB
    float* bn2 = (float*)(ws + 29820928);                           // 2 KB
    float* bn3 = (float*)(ws + 29822976);                           // 8 KB

    prep_w<<<2304, 256, 0, stream>>>(w1, w2, w3,
                                     g1, b1, m1, v1, g2, b2, m2, v2, g3, b3, m3, v3,
                                     Wb1, Wt2, Wb3, bn1, bn2, bn3, (uint4*)y1p);

    conv1_mfma<<<784, 256, 0, stream>>>(x, Wb1, bn1, y1p);
    conv2_mfma<<<784, 256, 0, stream>>>(y1p, Wt2, bn2, y2);
    conv3_mfma<<<dim3(196, 8), 256, 0, stream>>>(y2, Wb3, bn3, x, out);
}

// Round 9
// 303.431 us; speedup vs baseline: 1.0628x; 1.0628x over previous
//
#include <hip/hip_runtime.h>
#include <hip/hip_bf16.h>

// SpatialBottleneck — bf16 MFMA implicit-GEMM (NHWC).
// Round 13: two measured reverts. (a) XCD-pairing swizzle (r12) cut FETCH
// 93->71 MB but cost +5 µs on conv1 (paired blocks serialize cold misses on
// one L2) -> natural grid restored. (b) conv2 returns to BMT=128 fat steps
// (392 blocks x 36 steps), undoing the round-1 thin-tile edit that doubled
// per-step fixed costs (r0->r3 bookkeeping: conv1 -12 µs yet total +3 ->
// conv2 regressed ~+15). Fat conv2 now gets the counted-vmcnt dbuf pipeline
// it never had. Keep: cvt_pk (VALUBusy 16.5->12.8 confirmed), merged
// prep+border, counted vmcnt(8).

#define BK 64
#define WAITVM(N) asm volatile("s_waitcnt vmcnt(" #N ")" ::: "memory")

typedef __attribute__((ext_vector_type(8))) short short8;
typedef __attribute__((ext_vector_type(4))) float f32x4;

__device__ inline unsigned short f2bf(float f) {
    unsigned int u = __float_as_uint(f);
    u += 0x7fff + ((u >> 16) & 1);            // RNE (cold paths only)
    return (unsigned short)(u >> 16);
}

// Packed fp32->bf16 (RNE) via standard header; compiler emits the HW
// packed convert on gfx950.
__device__ inline unsigned cvt_pk_bf16(float a, float b) {
    __hip_bfloat162 h = __float22bfloat162_rn(make_float2(a, b)); // x=lo, y=hi
    return *reinterpret_cast<unsigned*>(&h);
}

__device__ inline void gload16(const unsigned short* g, unsigned short* l) {
    __builtin_amdgcn_global_load_lds(
        (const __attribute__((address_space(1))) unsigned int*)g,
        (__attribute__((address_space(3))) unsigned int*)l, 16, 0, 0);
}

// ---------------- prep: weights -> bf16, w2 -> [tap][co][ci]; BN fold;
// + y1p border zero (merged) ----------------
__global__ __launch_bounds__(256) void prep_w(
    const float* __restrict__ w1, const float* __restrict__ w2, const float* __restrict__ w3,
    const float* g1, const float* b1, const float* m1, const float* v1,
    const float* g2, const float* b2, const float* m2, const float* v2,
    const float* g3, const float* b3, const float* m3, const float* v3,
    unsigned short* __restrict__ Wb1, unsigned short* __restrict__ Wt2,
    unsigned short* __restrict__ Wb3,
    float* __restrict__ bn1, float* __restrict__ bn2, float* __restrict__ bn3,
    uint4* __restrict__ y1p) {
    int i = blockIdx.x * 256 + threadIdx.x;
    if (i < 262144) Wb1[i] = f2bf(w1[i]);
    if (i < 589824) {
        int kw = i % 3, t1 = i / 3;
        int kh = t1 % 3, t2 = t1 / 3;
        int ci = t2 & 255, co = t2 >> 8;
        Wt2[(size_t)((kh * 3 + kw) * 256 + co) * 256 + ci] = f2bf(w2[i]);
    }
    if (i < 262144) Wb3[i] = f2bf(w3[i]);
    if (i < 256) { float s = g1[i] * rsqrtf(v1[i]); bn1[i] = s; bn1[256 + i] = b1[i] - m1[i] * s; }
    if (i < 256) { float s = g2[i] * rsqrtf(v2[i]); bn2[i] = s; bn2[256 + i] = b2[i] - m2[i] * s; }
    if (i < 1024) { float s = g3[i] * rsqrtf(v3[i]); bn3[i] = s; bn3[1024 + i] = b3[i] - m3[i] * s; }
    // y1p border zero: 118784 = 32 img * 116 border cells * 32 uint4
    if (i < 118784) {
        int ch8 = i & 31;
        int t = i >> 5;
        int cell = t % 116;
        int n = t / 116;
        int h, w;
        if (cell < 30)      { h = 0;          w = cell; }
        else if (cell < 60) { h = 29;         w = cell - 30; }
        else if (cell < 88) { h = cell - 59;  w = 0; }
        else                { h = cell - 87;  w = 29; }
        y1p[((size_t)n * 900 + h * 30 + w) * 32 + ch8] = make_uint4(0u, 0u, 0u, 0u);
    }
}

// ---------------- MFMA implicit-GEMM conv body (counted-vmcnt pipeline) ----------------
// LAYER 1: x fp32 NCHW in (fused transpose/convert), y1p padded NHWC bf16 out
// LAYER 2: y1p in (9-tap), y2 NHWC bf16 out
// LAYER 3: y2 in, fp32 NCHW out + residual
template <int CX, int NTAPS, int LAYER, int NT, int BMT>
__device__ __forceinline__ void conv_body(
    const float* __restrict__ Xf,
    const unsigned short* __restrict__ Xg, const unsigned short* __restrict__ Wg,
    const float* __restrict__ bn, int nco,
    const float* __restrict__ residual,
    unsigned short* __restrict__ obf, float* __restrict__ ofp) {
    constexpr int KSTEPS = CX / BK;               // k0 steps per tap
    constexpr int NSTEP = NTAPS * KSTEPS;         // 16 / 36 / 4
    constexpr int XB = BMT * BK * 2;              // bytes per X buffer
    constexpr int WB = NT * BK * 2;               // bytes per W buffer
    constexpr int STAGEB = 2 * (XB + WB);         // 48K (l1), 64K (l2/l3)
    constexpr int EPIB = (LAYER == 3) ? 64 * 132 * 4 : 64 * (NT + 8) * 2;
    constexpr int SMEMB = STAGEB > EPIB ? STAGEB : EPIB;
    constexpr int NWJ = BMT / 32;                 // px fragments per wave
    constexpr int WR = NT / 32;                   // W staging rounds (4)
    constexpr int XR = BMT / 32;                  // X staging rounds (l2/l3)

    __shared__ __align__(16) char smem[SMEMB];
    unsigned short* const Xs0 = (unsigned short*)smem;
    unsigned short* const Xs1 = (unsigned short*)(smem + XB);
    unsigned short* const Ws0 = (unsigned short*)(smem + 2 * XB);
    unsigned short* const Ws1 = (unsigned short*)(smem + 2 * XB + WB);

    const int tid = threadIdx.x;
    const int wave = tid >> 6, lane = tid & 63;
    const int quad = lane >> 4, l15 = lane & 15;
    const int Pb = blockIdx.x * BMT;
    const int cb = blockIdx.y * NT;
    const int wco = (wave & 1) * 64;
    const int wpx = (wave >> 1) * (BMT / 2);

    // ---- staging precompute ----
    size_t wro[WR];                               // W: per-round global row offset
    #pragma unroll
    for (int t = 0; t < WR; ++t) {
        int slot = t * 256 + tid;
        int row = slot >> 3;
        int c = slot & 7;
        wro[t] = (size_t)(cb + row) * CX + ((c ^ (row & 7)) * 8);
    }

    int cso[4];
    size_t xrow[4];
    if (LAYER != 1) {
        #pragma unroll
        for (int t = 0; t < XR; ++t) {
            int slot = t * 256 + tid;
            int row = slot >> 3;
            int c = slot & 7;
            cso[t] = ((c ^ (row & 7)) * 8);
            if (LAYER == 2) {
                int P = Pb + row;
                int n = P / 784, rem = P - n * 784;
                int h = rem / 28, w = rem - h * 28;
                xrow[t] = (size_t)n * 900 + h * 30 + w;   // padded base (tap adds kh*30+kw)
            } else {
                xrow[t] = (size_t)(Pb + row);
            }
        }
    }

    // LAYER 1: coalesced transpose staging (4-lane groups read 64B contiguous)
    const int cpl = (lane >> 2) + (wave & 1) * 16;   // channel-pair 0..31
    size_t xbase[2];
    int plr[2];
    if (LAYER == 1) {
        #pragma unroll
        for (int r = 0; r < 2; ++r) {
            int quarter = (wave >> 1) + 2 * r;       // 0..3
            int pl = quarter * 16 + (lane & 3) * 4;  // 0..60
            int P = Pb + pl;
            int n = P / 784, p = P - n * 784;        // float4 never crosses n (784%4==0)
            plr[r] = pl;
            xbase[r] = ((size_t)n * 1024 + 2 * cpl) * 784 + p;
        }
    }

    // ---- stage helpers ----
    auto stageW = [&](int s, unsigned short* wsb) {
        int tap = (NTAPS == 1) ? 0 : (s / KSTEPS);
        int k0 = (s - tap * KSTEPS) * BK;
        const unsigned short* Wtap = Wg + (size_t)tap * 256 * CX;
        #pragma unroll
        for (int t = 0; t < WR; ++t)
            gload16(Wtap + wro[t] + k0, wsb + (t * 256 + wave * 64) * 8);
    };
    auto stageX = [&](int s, unsigned short* xsb) {   // layers 2/3
        int tap = (NTAPS == 1) ? 0 : (s / KSTEPS);
        int k0 = (s - tap * KSTEPS) * BK;
        int tapofs = (NTAPS == 9) ? ((tap / 3) * 30 + (tap % 3)) : 0;
        #pragma unroll
        for (int t = 0; t < XR; ++t)
            gload16(Xg + (xrow[t] + tapofs) * (size_t)CX + k0 + cso[t],
                    xsb + (t * 256 + wave * 64) * 8);
    };
    float4 xa[2], xb[2];                              // layer-1 in-flight regs
    auto loadX1 = [&](int s) {
        size_t k0 = (size_t)s * BK;
        #pragma unroll
        for (int r = 0; r < 2; ++r) {
            const float* src = Xf + xbase[r] + k0 * 784;
            xa[r] = *(const float4*)src;
            xb[r] = *(const float4*)(src + 784);
        }
    };
    auto convW1 = [&](unsigned short* xsb) {
        #pragma unroll
        for (int r = 0; r < 2; ++r) {
            float av[4] = {xa[r].x, xa[r].y, xa[r].z, xa[r].w};
            float bv[4] = {xb[r].x, xb[r].y, xb[r].z, xb[r].w};
            #pragma unroll
            for (int j = 0; j < 4; ++j) {
                unsigned u = cvt_pk_bf16(av[j], bv[j]);   // HW RNE pack
                int row = plr[r] + j;
                int dw = row * 32 + (((cpl >> 2) ^ (row & 7)) << 2) + (cpl & 3);
                ((unsigned*)xsb)[dw] = u;
            }
        }
    };

    f32x4 acc[4][NWJ];
    #pragma unroll
    for (int i = 0; i < 4; ++i)
        #pragma unroll
        for (int j = 0; j < NWJ; ++j)
            acc[i][j] = (f32x4){0.f, 0.f, 0.f, 0.f};

    auto compute = [&](const unsigned short* xsb, const unsigned short* wsb) {
        #pragma unroll
        for (int kk = 0; kk < BK; kk += 32) {
            short8 af[4], bf[NWJ];
            const int cbase = kk >> 3;            // 0 or 4
            #pragma unroll
            for (int wi = 0; wi < 4; ++wi) {
                int row = wco + wi * 16 + l15;
                int ch = (cbase + quad) ^ (row & 7);
                af[wi] = *(const short8*)(wsb + (row * 8 + ch) * 8);
            }
            #pragma unroll
            for (int wj = 0; wj < NWJ; ++wj) {
                int row = wpx + wj * 16 + l15;
                int ch = (cbase + quad) ^ (row & 7);
                bf[wj] = *(const short8*)(xsb + (row * 8 + ch) * 8);
            }
            #pragma unroll
            for (int wi = 0; wi < 4; ++wi)
                #pragma unroll
                for (int wj = 0; wj < NWJ; ++wj)
                    acc[wi][wj] = __builtin_amdgcn_mfma_f32_16x16x32_bf16(
                        af[wi], bf[wj], acc[wi][wj], 0, 0, 0);
        }
    };

    // ---- prologue: batch(0) into buffer 0 ----
    if (LAYER == 1) loadX1(0);
    stageW(0, Ws0);
    if (LAYER == 1) convW1(Xs0);                  // compiler waits on xa/xb regs
    else            stageX(0, Xs0);

    // ---- counted-vmcnt pipelined loop ----
    int cur = 0;
    #pragma unroll 1
    for (int s = 0; s < NSTEP; ++s) {
        unsigned short* xc = cur ? Xs1 : Xs0;
        unsigned short* wc = cur ? Ws1 : Ws0;
        unsigned short* xn = cur ? Xs0 : Xs1;
        unsigned short* wn = cur ? Ws0 : Ws1;
        const bool pre = (s + 1 < NSTEP);
        if (pre) {
            if (LAYER == 1) loadX1(s + 1);        // 4 float4 (oldest in batch)
            stageW(s + 1, wn);                    // 4 gload_lds
            if (LAYER != 1) stageX(s + 1, xn);    // 4 gload_lds
        }
        // Wait: batch(s) landed; batch(s+1) (8 vmem instrs) stays in flight.
        if (pre) WAITVM(8);
        else     WAITVM(0);
        __builtin_amdgcn_sched_barrier(0);
        __builtin_amdgcn_s_barrier();             // A: buffers for step s visible
        compute(xc, wc);
        if (LAYER == 1 && pre) convW1(xn);        // write-late: cvt_pk + ds_write
        if (LAYER == 1) asm volatile("s_waitcnt lgkmcnt(0)" ::: "memory");
        __builtin_amdgcn_s_barrier();             // B: compute(s) done; xn writes visible
        __builtin_amdgcn_sched_barrier(0);
        cur ^= 1;
    }

    __syncthreads();   // epilogue smem reuse

    if (LAYER == 3) {
        // fp32 NCHW + residual + ReLU, two co-half passes through LDS [64][132] f32
        float* ep = (float*)smem;
        #pragma unroll
        for (int pass = 0; pass < 2; ++pass) {
            if ((wave & 1) == pass) {
                #pragma unroll
                for (int wi = 0; wi < 4; ++wi) {
                    int co0 = cb + wco + wi * 16 + quad * 4;
                    f32x4 sc = *(const f32x4*)(bn + co0);
                    f32x4 bi = *(const f32x4*)(bn + nco + co0);
                    int cr0 = wi * 16 + quad * 4;          // 0..63 local co row
                    #pragma unroll
                    for (int wj = 0; wj < 4; ++wj) {
                        int px = wpx + wj * 16 + l15;      // 0..127
                        #pragma unroll
                        for (int r = 0; r < 4; ++r)
                            ep[(cr0 + r) * 132 + px] = fmaf(acc[wi][wj][r], sc[r], bi[r]);
                    }
                }
            }
            __syncthreads();
            {
                int cr = tid >> 2;                         // 0..63
                int cg = tid & 3;
                int co = cb + pass * 64 + cr;
                #pragma unroll
                for (int k = 0; k < 8; ++k) {
                    int px4 = (cg + 4 * k) * 4;            // 0..124
                    f32x4 v = *(const f32x4*)(ep + cr * 132 + px4);
                    int P = Pb + px4;
                    int n = P / 784, p = P - n * 784;
                    size_t off = ((size_t)n * 1024 + co) * 784 + p;
                    float4 rs = *(const float4*)(residual + off);
                    float4 o;
                    o.x = v[0] + rs.x; o.x = o.x > 0.f ? o.x : 0.f;
                    o.y = v[1] + rs.y; o.y = o.y > 0.f ? o.y : 0.f;
                    o.z = v[2] + rs.z; o.z = o.z > 0.f ? o.z : 0.f;
                    o.w = v[3] + rs.w; o.w = o.w > 0.f ? o.w : 0.f;
                    *(float4*)(ofp + off) = o;
                }
            }
            __syncthreads();
        }
    } else {
        // bf16 NHWC (+BN+ReLU), BMT/64 px-half passes through LDS [64][NT+8] ushort
        constexpr int NPASS = BMT / 64;            // 1 (l1) or 2 (l2)
        constexpr int EPW = NT + 8;                // 136
        unsigned short* ep = (unsigned short*)smem;
        #pragma unroll
        for (int pass = 0; pass < NPASS; ++pass) {
            if (NPASS == 1 || (wave >> 1) == pass) {
                #pragma unroll
                for (int wi = 0; wi < 4; ++wi) {
                    int co0 = cb + wco + wi * 16 + quad * 4;
                    f32x4 sc = *(const f32x4*)(bn + co0);
                    f32x4 bi = *(const f32x4*)(bn + nco + co0);
                    int col = wco + wi * 16 + quad * 4;    // 0..127 local co
                    #pragma unroll
                    for (int wj = 0; wj < NWJ; ++wj) {
                        int pxl = (wpx & 63) + wj * 16 + l15;  // 0..63 within pass
                        float v0 = fmaf(acc[wi][wj][0], sc[0], bi[0]); v0 = v0 > 0.f ? v0 : 0.f;
                        float v1 = fmaf(acc[wi][wj][1], sc[1], bi[1]); v1 = v1 > 0.f ? v1 : 0.f;
                        float v2 = fmaf(acc[wi][wj][2], sc[2], bi[2]); v2 = v2 > 0.f ? v2 : 0.f;
                        float v3 = fmaf(acc[wi][wj][3], sc[3], bi[3]); v3 = v3 > 0.f ? v3 : 0.f;
                        uint2 pk;
                        pk.x = cvt_pk_bf16(v0, v1);
                        pk.y = cvt_pk_bf16(v2, v3);
                        *(uint2*)(ep + pxl * EPW + col) = pk;
                    }
                }
            }
            __syncthreads();
            {
                int pxl = tid >> 2;                    // 0..63
                int cg = tid & 3;
                int P = Pb + pass * 64 + pxl;
                size_t orow;
                if (LAYER == 1) {
                    int n = P / 784, rem = P - n * 784;
                    int h = rem / 28, w = rem - h * 28;
                    orow = (size_t)n * 900 + (h + 1) * 30 + (w + 1);
                } else {
                    orow = (size_t)P;
                }
                #pragma unroll
                for (int k = 0; k < NT / 32; ++k) {
                    int cc = (cg + 4 * k) * 8;         // ushort offset 0..120
                    uint4 v = *(const uint4*)(ep + pxl * EPW + cc);
                    *(uint4*)(obf + orow * 256 + cb + cc) = v;
                }
            }
            if (pass + 1 < NPASS) __syncthreads();
        }
    }
}

__global__ __launch_bounds__(256) void conv1_mfma(
    const float* __restrict__ Xf, const unsigned short* __restrict__ Wg,
    const float* __restrict__ bn, unsigned short* __restrict__ obf) {
    conv_body<1024, 1, 1, 128, 64>(Xf, nullptr, Wg, bn, 256, nullptr, obf, nullptr);
}
__global__ __launch_bounds__(256) void conv2_mfma(
    const unsigned short* __restrict__ Xg, const unsigned short* __restrict__ Wg,
    const float* __restrict__ bn, unsigned short* __restrict__ obf) {
    conv_body<256, 9, 2, 128, 128>(nullptr, Xg, Wg, bn, 256, nullptr, obf, nullptr);
}
__global__ __launch_bounds__(256) void conv3_mfma(
    const unsigned short* __restrict__ Xg, const unsigned short* __restrict__ Wg,
    const float* __restrict__ bn, const float* __restrict__ residual,
    float* __restrict__ ofp) {
    conv_body<256, 1, 3, 128, 128>(nullptr, Xg, Wg, bn, 1024, residual, nullptr, ofp);
}

extern "C" void kernel_launch(void* const* d_in, const int* in_sizes, int n_in,
                              void* d_out, int out_size, void* d_ws, size_t ws_size,
                              hipStream_t stream) {
    const float* x  = (const float*)d_in[0];
    const float* w1 = (const float*)d_in[1];
    const float* w2 = (const float*)d_in[2];
    const float* w3 = (const float*)d_in[3];
    const float* g1 = (const float*)d_in[4];  const float* b1 = (const float*)d_in[5];
    const float* m1 = (const float*)d_in[6];  const float* v1 = (const float*)d_in[7];
    const float* g2 = (const float*)d_in[8];  const float* b2 = (const float*)d_in[9];
    const float* m2 = (const float*)d_in[10]; const float* v2 = (const float*)d_in[11];
    const float* g3 = (const float*)d_in[12]; const float* b3 = (const float*)d_in[13];
    const float* m3 = (const float*)d_in[14]; const float* v3 = (const float*)d_in[15];
    float* out = (float*)d_out;

    char* ws = (char*)d_ws;
    unsigned short* y1p = (unsigned short*)(ws);                    // 32*900*256*2 = 14,745,600
    unsigned short* y2  = (unsigned short*)(ws + 14745600);         // 25088*256*2  = 12,845,056
    unsigned short* Wb1 = (unsigned short*)(ws + 27590656);         // 524,288
    unsigned short* Wt2 = (unsigned short*)(ws + 28114944);         // 1,179,648
    unsigned short* Wb3 = (unsigned short*)(ws + 29294592);         // 524,288
    float* bn1 = (float*)(ws + 29818880);                           // 2 KB
    float* bn2 = (float*)(ws + 29820928);                           // 2 KB
    float* bn3 = (float*)(ws + 29822976);                           // 8 KB

    prep_w<<<2304, 256, 0, stream>>>(w1, w2, w3,
                                     g1, b1, m1, v1, g2, b2, m2, v2, g3, b3, m3, v3,
                                     Wb1, Wt2, Wb3, bn1, bn2, bn3, (uint4*)y1p);

    conv1_mfma<<<dim3(392, 2), 256, 0, stream>>>(x, Wb1, bn1, y1p);
    conv2_mfma<<<dim3(196, 2), 256, 0, stream>>>(y1p, Wt2, bn2, y2);
    conv3_mfma<<<dim3(196, 8), 256, 0, stream>>>(y2, Wb3, bn3, x, out);
}